// Round 6
// baseline (45.813 us; speedup 1.0000x reference)
//
#include <hip/hip_runtime.h>
#include <hip/hip_bf16.h>
#include <stdint.h>

// PWB linear layer: out = relu(x @ q(W) + q(b)), q = round(clip(t,-1,1)*127)/127
// R6: LDS-traffic-optimized i8 GEMM: BM=256 BN=128 BK=64, 4 waves of 128x64
// (reads/MFMA 0.375KB vs 0.5KB) -> total LDS traffic 786->590 MB. Grid=256 =
// 1 block/CU, LDS 72KB, 3-buffer pipeline, counted vmcnt(6). Pre-passes merged
// into one kernel (x-rows + W-tiles by block range).

typedef __attribute__((ext_vector_type(4))) int i32x4;

#define BM 256
#define BN 128
#define BK 64   // i8: 64 B per row per tile = 4 x 16B chunks

__device__ __forceinline__ float pwb_clip(float w) {
    return fminf(fmaxf(w, -1.f), 1.f);
}

__device__ __forceinline__ void gl16(const int8_t* g, int8_t* l) {
    __builtin_amdgcn_global_load_lds(
        (const __attribute__((address_space(1))) void*)(g),
        (__attribute__((address_space(3))) void*)(l),
        16, 0, 0);
}

#define WAIT_LGKM0 { asm volatile("s_waitcnt lgkmcnt(0)" ::: "memory"); \
                     __builtin_amdgcn_sched_barrier(0); }
#define WAIT_VM6   asm volatile("s_waitcnt vmcnt(6)" ::: "memory");
#define WAIT_VM0   asm volatile("s_waitcnt vmcnt(0)" ::: "memory");
#define BAR()      __builtin_amdgcn_s_barrier();

// ---- merged pre-pass: blocks [0,xblocks) quantize x rows (per-row i8);
//      blocks [xblocks,...) quantize+transpose W 32x32 tiles ----
__global__ void pwb_prep(const float* __restrict__ x, const float* __restrict__ W,
                         int8_t* __restrict__ xq, int8_t* __restrict__ Wq,
                         float* __restrict__ scales, int DIN, int DOUT, int xblocks) {
    __shared__ int8_t t[32][36];
    const int tid = threadIdx.x;
    if ((int)blockIdx.x < xblocks) {
        // ---- x path: one wave per row, two-pass (no scratch arrays) ----
        const int row = blockIdx.x * 4 + (tid >> 6);
        const int l   = tid & 63;
        const float4* xr = (const float4*)(x + (size_t)row * DIN);
        const int J = DIN >> 8;            // float4-groups per lane
        float m = 0.f;
        for (int j = 0; j < J; ++j) {
            float4 v = xr[j * 64 + l];
            m = fmaxf(m, fmaxf(fmaxf(fabsf(v.x), fabsf(v.y)),
                               fmaxf(fabsf(v.z), fabsf(v.w))));
        }
#pragma unroll
        for (int d = 1; d < 64; d <<= 1) m = fmaxf(m, __shfl_xor(m, d));
        const float r = (m > 0.f) ? 127.f / m : 0.f;
        if (l == 0) scales[row] = m / 16129.f;     // rowmax / 127^2
        uint32_t* o = (uint32_t*)(xq + (size_t)row * DIN);
        for (int j = 0; j < J; ++j) {
            float4 v = xr[j * 64 + l];             // L1-hit re-read
            int q0 = (int)rintf(v.x * r), q1 = (int)rintf(v.y * r);
            int q2 = (int)rintf(v.z * r), q3 = (int)rintf(v.w * r);
            uint32_t u = (uint32_t)(q0 & 255) | ((uint32_t)(q1 & 255) << 8) |
                         ((uint32_t)(q2 & 255) << 16) | ((uint32_t)(q3 & 255) << 24);
            o[j * 64 + l] = u;
        }
    } else {
        // ---- W path: quantize + transpose 32x32 tile -> Wq[DOUT][DIN] i8 ----
        const int wb = blockIdx.x - xblocks;
        const int gw = DOUT >> 5;
        const int c0 = (wb % gw) * 32;   // DOUT base
        const int r0 = (wb / gw) * 32;   // DIN base
        const int tx = tid & 31, ty = tid >> 5;   // 32 x 8
#pragma unroll
        for (int i = 0; i < 4; ++i) {
            int row = r0 + ty + i * 8;
            float w = W[(size_t)row * DOUT + c0 + tx];
            t[tx][ty + i * 8] = (int8_t)rintf(pwb_clip(w) * 127.f);
        }
        __syncthreads();
        // 256 threads: tid>>3 = local DOUT row (0..31), tid&7 = 4B word in DIN
        const int lr = tid >> 3, wd = tid & 7;
        uint32_t u = (uint32_t)(uint8_t)t[lr][wd * 4 + 0]
                   | ((uint32_t)(uint8_t)t[lr][wd * 4 + 1] << 8)
                   | ((uint32_t)(uint8_t)t[lr][wd * 4 + 2] << 16)
                   | ((uint32_t)(uint8_t)t[lr][wd * 4 + 3] << 24);
        ((uint32_t*)(Wq + (size_t)(c0 + lr) * DIN + r0))[wd] = u;
    }
}

// ================= main GEMM (i8) =================
// C[M][N] = relu( (A[M][K]i8 x Bt[N][K]i8) * scales[row] + q(b)[col] )
__global__ __launch_bounds__(256, 1) void pwb_gemmq(
    const int8_t* __restrict__ A,    // [M][K] i8
    const int8_t* __restrict__ Bt,   // [N][K] i8
    const float* __restrict__ scales,// [M] rowmax/127^2
    const float* __restrict__ b,     // [N] raw bias (quantized inline)
    float* __restrict__ C,           // [M][N] f32
    int M, int N, int K, int GN, int nwg) {
    // 3 buffers: A 16KB + B 8KB each -> 72 KiB total (1 block/CU)
    __shared__ __align__(16) int8_t lA[3][BM * BK];
    __shared__ __align__(16) int8_t lB[3][BN * BK];

    const int tid = threadIdx.x;
    const int w   = tid >> 6;     // 0..3
    const int l   = tid & 63;
    const int lr  = l & 15;
    const int lk  = l >> 4;       // 0..3 (k-chunk of 16 i8)

    // bijective XCD swizzle (m204)
    const int bid = blockIdx.x;
    const int q = nwg >> 3, r = nwg & 7;
    const int xcd = bid & 7, lin = bid >> 3;
    const int wgid = (xcd < r ? xcd * (q + 1) : r * (q + 1) + (xcd - r) * q) + lin;
    const int tm = wgid / GN, tn = wgid % GN;
    const size_t brow = (size_t)tm * BM, bcol = (size_t)tn * BN;

    const int wm = (w >> 1) * 128;  // wave M offset (0/128), wave tile 128x64
    const int wn = (w & 1) * 64;    // wave N offset (0/64)

    // ---- staging source addrs: chunk s = tid + 256*i; row = s>>2, slot s&3
    //      holds global k-chunk (s&3)^((s>>3)&3)  [inverse swizzle; linear LDS
    //      dest as global_load_lds requires] ----
    const int8_t* gAp[4];
    const int8_t* gBp[2];
#pragma unroll
    for (int i = 0; i < 4; ++i) {
        int s = tid + 256 * i;
        int rr = s >> 2, kc = (s & 3) ^ ((s >> 3) & 3);
        gAp[i] = A + (size_t)(brow + rr) * K + kc * 16;
    }
#pragma unroll
    for (int i = 0; i < 2; ++i) {
        int s = tid + 256 * i;
        int rr = s >> 2, kc = (s & 3) ^ ((s >> 3) & 3);
        gBp[i] = Bt + (size_t)(bcol + rr) * K + kc * 16;
    }

    // ---- ds_read byte offsets (row stride 64B; XOR involution on k-slot).
    //      row = wm|wn + f*16 + lr -> (row>>1)&3 == (lr>>1)&3 ----
    const int xk    = (lk ^ ((lr >> 1) & 3)) << 4;
    const int offAb = (wm + lr) * 64 + xk;
    const int offBb = (wn + lr) * 64 + xk;

    i32x4 acc[8][4] = {};

    const int T = K / BK;   // >= 2

#define STAGE(buf, ktg)                                \
    gl16(gAp[0] + (ktg), &lA[buf][w * 1024]);          \
    gl16(gAp[1] + (ktg), &lA[buf][w * 1024 + 4096]);   \
    gl16(gAp[2] + (ktg), &lA[buf][w * 1024 + 8192]);   \
    gl16(gAp[3] + (ktg), &lA[buf][w * 1024 + 12288]);  \
    gl16(gBp[0] + (ktg), &lB[buf][w * 1024]);          \
    gl16(gBp[1] + (ktg), &lB[buf][w * 1024 + 4096]);

#define DS_FRAGS(cA, cB)                                      \
    i32x4 af[8], bfr[4];                                      \
    _Pragma("unroll") for (int mi = 0; mi < 8; ++mi)          \
        af[mi] = *(const i32x4*)&(cA)[offAb + mi * 1024];     \
    _Pragma("unroll") for (int nj = 0; nj < 4; ++nj)          \
        bfr[nj] = *(const i32x4*)&(cB)[offBb + nj * 1024];

#define MFMA32                                                 \
    __builtin_amdgcn_s_setprio(1);                             \
    _Pragma("unroll") for (int mi = 0; mi < 8; ++mi)           \
    _Pragma("unroll") for (int nj = 0; nj < 4; ++nj)           \
        acc[mi][nj] = __builtin_amdgcn_mfma_i32_16x16x64_i8(   \
            af[mi], bfr[nj], acc[mi][nj], 0, 0, 0);            \
    __builtin_amdgcn_s_setprio(0);

    // ---- prologue: stage tiles 0,1 (12 loads/thread-group) ----
    STAGE(0, 0)
    STAGE(1, BK)
    WAIT_VM6        // tile 0 resident (tile 1's 6 still in flight)
    BAR();

    int cur = 0;
    // ---- main loop: compute tile t, prefetch tile t+2 ----
    for (int t = 0; t < T - 2; ++t) {
        int nb = cur + 2; if (nb >= 3) nb -= 3;
        const int8_t* cA = &lA[cur][0];
        const int8_t* cB = &lB[cur][0];
        {
            DS_FRAGS(cA, cB)
            STAGE(nb, (t + 2) * BK)
            BAR();
            WAIT_LGKM0
            MFMA32
        }
        WAIT_VM6    // tile t+1 resident; tile t+2's 6 loads stay in flight
        BAR();
        cur = (cur == 2) ? 0 : cur + 1;
    }
    // ---- tail iter T-2 ----
    {
        const int8_t* cA = &lA[cur][0];
        const int8_t* cB = &lB[cur][0];
        DS_FRAGS(cA, cB)
        BAR();
        WAIT_LGKM0
        MFMA32
        WAIT_VM0
        BAR();
        cur = (cur == 2) ? 0 : cur + 1;
    }
    // ---- tail iter T-1 ----
    {
        const int8_t* cA = &lA[cur][0];
        const int8_t* cB = &lB[cur][0];
        DS_FRAGS(cA, cB)
        WAIT_LGKM0
        MFMA32
    }

    // ---- epilogue: y = acc * scales[row] + q(b)[col], relu.
    //      C/D layout: col = lane&15, row = (lane>>4)*4 + reg ----
    float bias[4];
#pragma unroll
    for (int nj = 0; nj < 4; ++nj) {
        float bv = b[bcol + wn + nj * 16 + lr];
        bias[nj] = rintf(pwb_clip(bv) * 127.f) * (1.f / 127.f);
    }

    const size_t orow = brow + wm + lk * 4;   // multiple of 4
    const size_t ocol = bcol + wn + lr;
    float4 scl[8];
#pragma unroll
    for (int mi = 0; mi < 8; ++mi)
        scl[mi] = *(const float4*)&scales[orow + mi * 16];

#pragma unroll
    for (int mi = 0; mi < 8; ++mi) {
        const float s0 = scl[mi].x, s1 = scl[mi].y, s2 = scl[mi].z, s3 = scl[mi].w;
#pragma unroll
        for (int nj = 0; nj < 4; ++nj) {
            float v0 = fmaf((float)acc[mi][nj][0], s0, bias[nj]);
            float v1 = fmaf((float)acc[mi][nj][1], s1, bias[nj]);
            float v2 = fmaf((float)acc[mi][nj][2], s2, bias[nj]);
            float v3 = fmaf((float)acc[mi][nj][3], s3, bias[nj]);
            float* cp = &C[(orow + mi * 16) * N + (ocol + nj * 16)];
            cp[0 * N] = fmaxf(v0, 0.f);
            cp[1 * N] = fmaxf(v1, 0.f);
            cp[2 * N] = fmaxf(v2, 0.f);
            cp[3 * N] = fmaxf(v3, 0.f);
        }
    }
#undef STAGE
#undef DS_FRAGS
#undef MFMA32
}

// ---- fallback (any shape): fp32, on-the-fly quantize ----
__global__ void pwb_fallback(const float* __restrict__ x, const float* __restrict__ W,
                             const float* __restrict__ b, float* __restrict__ out,
                             int M, int N, int K) {
    __shared__ float sA[16][17];
    __shared__ float sB[16][17];
    int tx = threadIdx.x, ty = threadIdx.y;
    int row = blockIdx.y * 16 + ty;
    int col = blockIdx.x * 16 + tx;
    float acc = 0.f;
    for (int kt = 0; kt < K; kt += 16) {
        sA[ty][tx] = (row < M && kt + tx < K) ? x[(size_t)row * K + kt + tx] : 0.f;
        float w = (kt + ty < K && col < N) ? W[(size_t)(kt + ty) * N + col] : 0.f;
        sB[ty][tx] = rintf(pwb_clip(w) * 127.f) * (1.f / 127.f);
        __syncthreads();
#pragma unroll
        for (int kk = 0; kk < 16; ++kk) acc += sA[ty][kk] * sB[kk][tx];
        __syncthreads();
    }
    if (row < M && col < N) {
        float v = acc + rintf(pwb_clip(b[col]) * 127.f) * (1.f / 127.f);
        out[(size_t)row * N + col] = fmaxf(v, 0.f);
    }
}

extern "C" void kernel_launch(void* const* d_in, const int* in_sizes, int n_in,
                              void* d_out, int out_size, void* d_ws, size_t ws_size,
                              hipStream_t stream) {
    const float* x = (const float*)d_in[0];
    const float* W = (const float*)d_in[1];
    const float* b = (const float*)d_in[2];
    float* out = (float*)d_out;

    const int DOUT = in_sizes[2];
    const int DIN  = in_sizes[1] / DOUT;
    const int M    = in_sizes[0] / DIN;

    size_t need = (size_t)M * DIN + (size_t)DIN * DOUT + (size_t)M * 4;
    bool fast = (M % BM == 0) && (DOUT % BN == 0) &&
                (DIN % 256 == 0) && (DIN >= 2 * BK) &&
                (DOUT % 32 == 0) && (DIN % 32 == 0) && (ws_size >= need);

    if (fast) {
        int8_t* xq = (int8_t*)d_ws;                       // [M][K] i8
        int8_t* Wq = xq + (size_t)M * DIN;                // [N][K] i8
        float* scales = (float*)(Wq + (size_t)DIN * DOUT);// [M] f32

        const int xblocks = M / 4;
        const int wblocks = (DOUT / 32) * (DIN / 32);
        pwb_prep<<<xblocks + wblocks, 256, 0, stream>>>(x, W, xq, Wq, scales,
                                                        DIN, DOUT, xblocks);

        const int GM = M / BM, GN = DOUT / BN, nwg = GM * GN;
        pwb_gemmq<<<nwg, 256, 0, stream>>>(xq, Wq, scales, b, out, M, DOUT, DIN, GN, nwg);
    } else {
        dim3 g((DOUT + 15) / 16, (M + 15) / 16), blk(16, 16);
        pwb_fallback<<<g, blk, 0, stream>>>(x, W, b, out, M, DOUT, DIN);
    }
}

// Round 7
// 43.238 us; speedup vs baseline: 1.0596x; 1.0596x over previous
//
#include <hip/hip_runtime.h>
#include <hip/hip_bf16.h>
#include <stdint.h>

// PWB linear layer: out = relu(x @ q(W) + q(b)), q = round(clip(t,-1,1)*127)/127
// R7: back to BM=BN=128 / 2 blocks/CU (R6's BM=256 = 1 wave/SIMD regressed).
// New: fragment ping-pong pipeline -- MFMA on frags(t) overlaps ds_read of
// frags(t+1) from the already-staged buffer; ONE barrier per K-tile; 4 LDS
// buffers (64KB) so stage-writes are >=2 barrier epochs from queued reads.
// i8 path: q(W) exact in i8, x per-row i8, i32 accum, scale+bias+relu epilogue.

typedef __attribute__((ext_vector_type(4))) int i32x4;

#define BM 128
#define BN 128
#define BK 64   // i8: 64 B per row per tile = 4 x 16B chunks

__device__ __forceinline__ float pwb_clip(float w) {
    return fminf(fmaxf(w, -1.f), 1.f);
}

__device__ __forceinline__ void gl16(const int8_t* g, int8_t* l) {
    __builtin_amdgcn_global_load_lds(
        (const __attribute__((address_space(1))) void*)(g),
        (__attribute__((address_space(3))) void*)(l),
        16, 0, 0);
}

#define WAIT_VM4   asm volatile("s_waitcnt vmcnt(4)" ::: "memory");
#define WAIT_VM0   asm volatile("s_waitcnt vmcnt(0)" ::: "memory");
#define BAR()      __builtin_amdgcn_s_barrier();

// ---- merged pre-pass: blocks [0,xblocks) quantize x rows (per-row i8);
//      blocks [xblocks,...) quantize+transpose W 32x32 tiles ----
__global__ void pwb_prep(const float* __restrict__ x, const float* __restrict__ W,
                         int8_t* __restrict__ xq, int8_t* __restrict__ Wq,
                         float* __restrict__ scales, int DIN, int DOUT, int xblocks) {
    __shared__ int8_t t[32][36];
    const int tid = threadIdx.x;
    if ((int)blockIdx.x < xblocks) {
        // ---- x path: one wave per row, two-pass (no scratch arrays) ----
        const int row = blockIdx.x * 4 + (tid >> 6);
        const int l   = tid & 63;
        const float4* xr = (const float4*)(x + (size_t)row * DIN);
        const int J = DIN >> 8;            // float4-groups per lane
        float m = 0.f;
        for (int j = 0; j < J; ++j) {
            float4 v = xr[j * 64 + l];
            m = fmaxf(m, fmaxf(fmaxf(fabsf(v.x), fabsf(v.y)),
                               fmaxf(fabsf(v.z), fabsf(v.w))));
        }
#pragma unroll
        for (int d = 1; d < 64; d <<= 1) m = fmaxf(m, __shfl_xor(m, d));
        const float r = (m > 0.f) ? 127.f / m : 0.f;
        if (l == 0) scales[row] = m / 16129.f;     // rowmax / 127^2
        uint32_t* o = (uint32_t*)(xq + (size_t)row * DIN);
        for (int j = 0; j < J; ++j) {
            float4 v = xr[j * 64 + l];             // L1-hit re-read
            int q0 = (int)rintf(v.x * r), q1 = (int)rintf(v.y * r);
            int q2 = (int)rintf(v.z * r), q3 = (int)rintf(v.w * r);
            uint32_t u = (uint32_t)(q0 & 255) | ((uint32_t)(q1 & 255) << 8) |
                         ((uint32_t)(q2 & 255) << 16) | ((uint32_t)(q3 & 255) << 24);
            o[j * 64 + l] = u;
        }
    } else {
        // ---- W path: quantize + transpose 32x32 tile -> Wq[DOUT][DIN] i8 ----
        const int wb = blockIdx.x - xblocks;
        const int gw = DOUT >> 5;
        const int c0 = (wb % gw) * 32;   // DOUT base
        const int r0 = (wb / gw) * 32;   // DIN base
        const int tx = tid & 31, ty = tid >> 5;   // 32 x 8
#pragma unroll
        for (int i = 0; i < 4; ++i) {
            int row = r0 + ty + i * 8;
            float w = W[(size_t)row * DOUT + c0 + tx];
            t[tx][ty + i * 8] = (int8_t)rintf(pwb_clip(w) * 127.f);
        }
        __syncthreads();
        // 256 threads: tid>>3 = local DOUT row (0..31), tid&7 = 4B word in DIN
        const int lr = tid >> 3, wd = tid & 7;
        uint32_t u = (uint32_t)(uint8_t)t[lr][wd * 4 + 0]
                   | ((uint32_t)(uint8_t)t[lr][wd * 4 + 1] << 8)
                   | ((uint32_t)(uint8_t)t[lr][wd * 4 + 2] << 16)
                   | ((uint32_t)(uint8_t)t[lr][wd * 4 + 3] << 24);
        ((uint32_t*)(Wq + (size_t)(c0 + lr) * DIN + r0))[wd] = u;
    }
}

// ================= main GEMM (i8) =================
// C[M][N] = relu( (A[M][K]i8 x Bt[N][K]i8) * scales[row] + q(b)[col] )
__global__ __launch_bounds__(256, 2) void pwb_gemmq(
    const int8_t* __restrict__ A,    // [M][K] i8
    const int8_t* __restrict__ Bt,   // [N][K] i8
    const float* __restrict__ scales,// [M] rowmax/127^2
    const float* __restrict__ b,     // [N] raw bias (quantized inline)
    float* __restrict__ C,           // [M][N] f32
    int M, int N, int K, int GN, int nwg) {
    // 4 buffers: A 8KB + B 8KB each -> 64 KiB total (2 blocks/CU = 128KB)
    __shared__ __align__(16) int8_t lA[4][BM * BK];
    __shared__ __align__(16) int8_t lB[4][BN * BK];

    const int tid = threadIdx.x;
    const int w   = tid >> 6;     // 0..3
    const int l   = tid & 63;
    const int lr  = l & 15;
    const int lk  = l >> 4;       // 0..3 (k-chunk of 16 i8)

    // bijective XCD swizzle (m204)
    const int bid = blockIdx.x;
    const int q = nwg >> 3, r = nwg & 7;
    const int xcd = bid & 7, lin = bid >> 3;
    const int wgid = (xcd < r ? xcd * (q + 1) : r * (q + 1) + (xcd - r) * q) + lin;
    const int tm = wgid / GN, tn = wgid % GN;
    const size_t brow = (size_t)tm * BM, bcol = (size_t)tn * BN;

    const int wm = (w >> 1) * 64;   // wave M offset
    const int wn = (w & 1) * 64;    // wave N offset

    // ---- staging source addrs: chunk s = tid + 256*i (i=0,1); row = s>>2,
    //      slot = s&3 holds global k-chunk (s&3)^((s>>3)&3)  [inverse swizzle,
    //      linear LDS dest as global_load_lds requires] ----
    const int s0 = tid, s1 = tid + 256;
    const int r0c = s0 >> 2, k0c = (s0 & 3) ^ ((s0 >> 3) & 3);
    const int r1c = s1 >> 2, k1c = (s1 & 3) ^ ((s1 >> 3) & 3);
    const int8_t* gA0 = A  + (size_t)(brow + r0c) * K + k0c * 16;
    const int8_t* gA1 = A  + (size_t)(brow + r1c) * K + k1c * 16;
    const int8_t* gB0 = Bt + (size_t)(bcol + r0c) * K + k0c * 16;
    const int8_t* gB1 = Bt + (size_t)(bcol + r1c) * K + k1c * 16;

    // ---- ds_read byte offsets (row stride 64B; XOR involution on k-slot) ----
    const int xk    = (lk ^ ((lr >> 1) & 3)) << 4;
    const int offAb = (wm + lr) * 64 + xk;
    const int offBb = (wn + lr) * 64 + xk;

    i32x4 acc[4][4] = {};

    const int T = K / BK;   // even, >= 4 (gated by launcher)

#define STAGE(buf, ktg)                              \
    gl16(gA0 + (ktg), &lA[buf][w * 1024]);           \
    gl16(gA1 + (ktg), &lA[buf][w * 1024 + 4096]);    \
    gl16(gB0 + (ktg), &lB[buf][w * 1024]);           \
    gl16(gB1 + (ktg), &lB[buf][w * 1024 + 4096]);

#define LOADFRAGS(fa, fb, bi)                                  \
    _Pragma("unroll") for (int mi = 0; mi < 4; ++mi)           \
        fa[mi] = *(const i32x4*)&lA[bi][offAb + mi * 1024];    \
    _Pragma("unroll") for (int nj = 0; nj < 4; ++nj)           \
        fb[nj] = *(const i32x4*)&lB[bi][offBb + nj * 1024];

#define MFMA16(fa, fb)                                         \
    __builtin_amdgcn_s_setprio(1);                             \
    _Pragma("unroll") for (int mi = 0; mi < 4; ++mi)           \
    _Pragma("unroll") for (int nj = 0; nj < 4; ++nj)           \
        acc[mi][nj] = __builtin_amdgcn_mfma_i32_16x16x64_i8(   \
            fa[mi], fb[nj], acc[mi][nj], 0, 0, 0);             \
    __builtin_amdgcn_s_setprio(0);

    // ---- prologue: stage tiles 0,1; load frags(0) into set A ----
    STAGE(0, 0)
    STAGE(1, BK)
    WAIT_VM4        // tile 0 resident (tile 1's 4 still in flight)
    BAR();

    i32x4 aA[4], bA[4], aB[4], bB[4];
    LOADFRAGS(aA, bA, 0)

    // ---- main loop (2-unrolled ping-pong): iter t computes tile t while
    //      loading frags(t+1) and staging tile t+2. One barrier per tile. ----
    int bR = 1, bS = 2;     // (t+1)&3, (t+2)&3 at t=0
    int ktg = 2 * BK;
    const int halfIters = (T - 2) >> 1;
    for (int it = 0; it < halfIters; ++it) {
        // even tile: compute set A, load set B
        STAGE(bS, ktg)
        ktg += BK;
        WAIT_VM4            // frags-read buffer (bR) fully staged
        BAR();
        LOADFRAGS(aB, bB, bR)
        MFMA16(aA, bA)      // overlaps the 8 ds_reads above (no dep)
        bR = (bR + 1) & 3; bS = (bS + 1) & 3;
        // odd tile: compute set B, load set A
        STAGE(bS, ktg)
        ktg += BK;
        WAIT_VM4
        BAR();
        LOADFRAGS(aA, bA, bR)
        MFMA16(aB, bB)
        bR = (bR + 1) & 3; bS = (bS + 1) & 3;
    }
    // ---- tail: tiles T-2 (in set A) and T-1 ----
    WAIT_VM0                // tile T-1 staging complete
    BAR();
    LOADFRAGS(aB, bB, bR)   // frags(T-1)
    MFMA16(aA, bA)          // tile T-2
    MFMA16(aB, bB)          // tile T-1 (compiler inserts lgkm wait)

    // ---- epilogue: y = acc * scales[row] + q(b)[col], relu.
    //      C/D layout: col = lane&15, row = (lane>>4)*4 + reg ----
    float bias[4];
#pragma unroll
    for (int nj = 0; nj < 4; ++nj) {
        float bv = b[bcol + wn + nj * 16 + lr];
        bias[nj] = rintf(pwb_clip(bv) * 127.f) * (1.f / 127.f);
    }

    const size_t orow = brow + wm + lk * 4;   // multiple of 4
    const size_t ocol = bcol + wn + lr;
    float4 scl[4];
#pragma unroll
    for (int mi = 0; mi < 4; ++mi)
        scl[mi] = *(const float4*)&scales[orow + mi * 16];

#pragma unroll
    for (int mi = 0; mi < 4; ++mi) {
        const float s0_ = scl[mi].x, s1_ = scl[mi].y, s2_ = scl[mi].z, s3_ = scl[mi].w;
#pragma unroll
        for (int nj = 0; nj < 4; ++nj) {
            float v0 = fmaf((float)acc[mi][nj][0], s0_, bias[nj]);
            float v1 = fmaf((float)acc[mi][nj][1], s1_, bias[nj]);
            float v2 = fmaf((float)acc[mi][nj][2], s2_, bias[nj]);
            float v3 = fmaf((float)acc[mi][nj][3], s3_, bias[nj]);
            float* cp = &C[(orow + mi * 16) * N + (ocol + nj * 16)];
            cp[0 * N] = fmaxf(v0, 0.f);
            cp[1 * N] = fmaxf(v1, 0.f);
            cp[2 * N] = fmaxf(v2, 0.f);
            cp[3 * N] = fmaxf(v3, 0.f);
        }
    }
#undef STAGE
#undef LOADFRAGS
#undef MFMA16
}

// ---- fallback (any shape): fp32, on-the-fly quantize ----
__global__ void pwb_fallback(const float* __restrict__ x, const float* __restrict__ W,
                             const float* __restrict__ b, float* __restrict__ out,
                             int M, int N, int K) {
    __shared__ float sA[16][17];
    __shared__ float sB[16][17];
    int tx = threadIdx.x, ty = threadIdx.y;
    int row = blockIdx.y * 16 + ty;
    int col = blockIdx.x * 16 + tx;
    float acc = 0.f;
    for (int kt = 0; kt < K; kt += 16) {
        sA[ty][tx] = (row < M && kt + tx < K) ? x[(size_t)row * K + kt + tx] : 0.f;
        float w = (kt + ty < K && col < N) ? W[(size_t)(kt + ty) * N + col] : 0.f;
        sB[ty][tx] = rintf(pwb_clip(w) * 127.f) * (1.f / 127.f);
        __syncthreads();
#pragma unroll
        for (int kk = 0; kk < 16; ++kk) acc += sA[ty][kk] * sB[kk][tx];
        __syncthreads();
    }
    if (row < M && col < N) {
        float v = acc + rintf(pwb_clip(b[col]) * 127.f) * (1.f / 127.f);
        out[(size_t)row * N + col] = fmaxf(v, 0.f);
    }
}

extern "C" void kernel_launch(void* const* d_in, const int* in_sizes, int n_in,
                              void* d_out, int out_size, void* d_ws, size_t ws_size,
                              hipStream_t stream) {
    const float* x = (const float*)d_in[0];
    const float* W = (const float*)d_in[1];
    const float* b = (const float*)d_in[2];
    float* out = (float*)d_out;

    const int DOUT = in_sizes[2];
    const int DIN  = in_sizes[1] / DOUT;
    const int M    = in_sizes[0] / DIN;

    size_t need = (size_t)M * DIN + (size_t)DIN * DOUT + (size_t)M * 4;
    const int T = DIN / BK;
    bool fast = (M % BM == 0) && (M % 4 == 0) && (DOUT % BN == 0) &&
                (DIN % 256 == 0) && (T >= 4) && ((T & 1) == 0) &&
                (DOUT % 32 == 0) && (DIN % 32 == 0) && (ws_size >= need);

    if (fast) {
        int8_t* xq = (int8_t*)d_ws;                       // [M][K] i8
        int8_t* Wq = xq + (size_t)M * DIN;                // [N][K] i8
        float* scales = (float*)(Wq + (size_t)DIN * DOUT);// [M] f32

        const int xblocks = M / 4;
        const int wblocks = (DOUT / 32) * (DIN / 32);
        pwb_prep<<<xblocks + wblocks, 256, 0, stream>>>(x, W, xq, Wq, scales,
                                                        DIN, DOUT, xblocks);

        const int GM = M / BM, GN = DOUT / BN, nwg = GM * GN;
        pwb_gemmq<<<nwg, 256, 0, stream>>>(xq, Wq, scales, b, out, M, DOUT, DIN, GN, nwg);
    } else {
        dim3 g((DOUT + 15) / 16, (M + 15) / 16), blk(16, 16);
        pwb_fallback<<<g, blk, 0, stream>>>(x, W, b, out, M, DOUT, DIN);
    }
}

// Round 8
// 40.527 us; speedup vs baseline: 1.1305x; 1.0669x over previous
//
#include <hip/hip_runtime.h>
#include <hip/hip_bf16.h>
#include <stdint.h>

// PWB linear layer: out = relu(x @ q(W) + q(b)), q = round(clip(t,-1,1)*127)/127
// R8: i8 path, B operand DIRECT FROM GLOBAL (L2-resident Wq) in 16x64-tiled
// layout -> LDS holds only A (4 x 8KB buffers). Tiled layouts make A-staging,
// ds_reads, and B-frag loads all contiguous (no swizzle needed, 0 conflicts).
// GEMM now MFMA-bound (~9us floor) instead of LDS-bound (~15us).
// Prep: x quantized via LDS staging (single HBM read); W in 64x64 blocks.
// Layouts: xq[M/16][K/64][16][64] i8, Wq[N/16][K/64][16][64] i8.

typedef __attribute__((ext_vector_type(4))) int i32x4;

#define BM 128
#define BN 128
#define BK 64

__device__ __forceinline__ float pwb_clip(float w) {
    return fminf(fmaxf(w, -1.f), 1.f);
}

__device__ __forceinline__ void gl16(const int8_t* g, int8_t* l) {
    __builtin_amdgcn_global_load_lds(
        (const __attribute__((address_space(1))) void*)(g),
        (__attribute__((address_space(3))) void*)(l),
        16, 0, 0);
}

#define WAIT_VM6   asm volatile("s_waitcnt vmcnt(6)" ::: "memory");
#define WAIT_VM4   asm volatile("s_waitcnt vmcnt(4)" ::: "memory");
#define WAIT_VM2   asm volatile("s_waitcnt vmcnt(2)" ::: "memory");
#define WAIT_VM0   asm volatile("s_waitcnt vmcnt(0)" ::: "memory");
#define BAR()      __builtin_amdgcn_s_barrier();

// ---- merged pre-pass ----
// blocks [0,xblocks): x rows -> per-row i8 (LDS-staged single HBM read), tiled
// blocks [xblocks,..): W 64x64 tiles -> quantize+transpose, tiled Wq
__global__ void pwb_prep(const float* __restrict__ x, const float* __restrict__ W,
                         int8_t* __restrict__ xq, int8_t* __restrict__ Wq,
                         float* __restrict__ scales, int DIN, int DOUT, int xblocks) {
    __shared__ __align__(16) float smem[4 * 2048];   // 32KB
    const int tid = threadIdx.x;
    const size_t KB = (size_t)(DIN >> 6) << 10;      // bytes per 16-row block-row

    if ((int)blockIdx.x < xblocks) {
        // ---- x path: one wave per row; stage row in LDS, quantize from LDS ----
        const int wv = tid >> 6, l = tid & 63;
        const int row = blockIdx.x * 4 + wv;
        const float4* xr = (const float4*)(x + (size_t)row * DIN);
        float* xs = smem + wv * 2048;
        const int J = DIN >> 8;                      // float4 groups per lane
        float m = 0.f;
        for (int j = 0; j < J; ++j) {
            float4 v = xr[j * 64 + l];
            *(float4*)&xs[j * 256 + l * 4] = v;
            m = fmaxf(m, fmaxf(fmaxf(fabsf(v.x), fabsf(v.y)),
                               fmaxf(fabsf(v.z), fabsf(v.w))));
        }
#pragma unroll
        for (int d = 1; d < 64; d <<= 1) m = fmaxf(m, __shfl_xor(m, d));
        const float r = (m > 0.f) ? 127.f / m : 0.f;
        if (l == 0) scales[row] = m / 16129.f;       // rowmax / 127^2
        // tiled dest: row block (row>>4), within-block row (row&15)
        int8_t* orow_ = xq + (size_t)(row >> 4) * KB + (row & 15) * 64;
        for (int j = 0; j < J; ++j) {
            float4 v = *(const float4*)&xs[j * 256 + l * 4];
            int q0 = (int)rintf(v.x * r), q1 = (int)rintf(v.y * r);
            int q2 = (int)rintf(v.z * r), q3 = (int)rintf(v.w * r);
            uint32_t u = (uint32_t)(q0 & 255) | ((uint32_t)(q1 & 255) << 8) |
                         ((uint32_t)(q2 & 255) << 16) | ((uint32_t)(q3 & 255) << 24);
            // k = j*256 + l*4 -> k-tile j*4 + (l>>4), in-tile byte (l&15)*4
            *(uint32_t*)(orow_ + (size_t)(j * 4 + (l >> 4)) * 1024 + (l & 15) * 4) = u;
        }
    } else {
        // ---- W path: 64(k) x 64(n) tile -> Wq tiled ----
        int8_t* tq = (int8_t*)smem;                  // [64][72] i8
        const int wb = blockIdx.x - xblocks;
        const int gw = DOUT >> 6;
        const int c0 = (wb % gw) * 64;               // n base
        const int r0 = (wb / gw) * 64;               // k base
        const int kl = tid >> 4;                     // 0..15
        const int nc = (tid & 15) * 4;               // 0..60
#pragma unroll
        for (int i = 0; i < 4; ++i) {
            int k = r0 + kl + i * 16;
            float4 wv = *(const float4*)&W[(size_t)k * DOUT + c0 + nc];
            tq[(nc + 0) * 72 + kl + i * 16] = (int8_t)rintf(pwb_clip(wv.x) * 127.f);
            tq[(nc + 1) * 72 + kl + i * 16] = (int8_t)rintf(pwb_clip(wv.y) * 127.f);
            tq[(nc + 2) * 72 + kl + i * 16] = (int8_t)rintf(pwb_clip(wv.z) * 127.f);
            tq[(nc + 3) * 72 + kl + i * 16] = (int8_t)rintf(pwb_clip(wv.w) * 127.f);
        }
        __syncthreads();
        const int nl = tid >> 2, cc = (tid & 3) * 16;
        uint32_t u0 = *(const uint32_t*)&tq[nl * 72 + cc + 0];
        uint32_t u1 = *(const uint32_t*)&tq[nl * 72 + cc + 4];
        uint32_t u2 = *(const uint32_t*)&tq[nl * 72 + cc + 8];
        uint32_t u3 = *(const uint32_t*)&tq[nl * 72 + cc + 12];
        const int n = c0 + nl;
        uint32_t* dst = (uint32_t*)(Wq + (size_t)(n >> 4) * KB +
                                    (size_t)(r0 >> 6) * 1024 + (n & 15) * 64 + cc);
        dst[0] = u0; dst[1] = u1; dst[2] = u2; dst[3] = u3;
    }
}

// ================= main GEMM (i8, B from global) =================
// C[M][N] = relu( (A x B^T) * scales[row] + q(b)[col] )
__global__ __launch_bounds__(256, 2) void pwb_gemmq(
    const int8_t* __restrict__ A,    // xq tiled [M/16][K/64][16][64]
    const int8_t* __restrict__ Bt,   // Wq tiled [N/16][K/64][16][64]
    const float* __restrict__ scales,// [M] rowmax/127^2
    const float* __restrict__ b,     // [N] raw bias (quantized inline)
    float* __restrict__ C,           // [M][N] f32
    int M, int N, int K, int GN, int nwg) {
    __shared__ __align__(16) int8_t lA[4][BM * BK];  // 4 x 8KB

    const int tid = threadIdx.x;
    const int w   = tid >> 6;     // 0..3
    const int l   = tid & 63;
    const int lr  = l & 15;
    const int lk  = l >> 4;       // 0..3

    // bijective XCD swizzle (m204)
    const int bid = blockIdx.x;
    const int q = nwg >> 3, r = nwg & 7;
    const int xcd = bid & 7, lin = bid >> 3;
    const int wgid = (xcd < r ? xcd * (q + 1) : r * (q + 1) + (xcd - r) * q) + lin;
    const int tm = wgid / GN, tn = wgid % GN;
    const size_t brow = (size_t)tm * BM, bcol = (size_t)tn * BN;

    const int wm = (w >> 1) * 64;   // wave M offset
    const int wn = (w & 1) * 64;    // wave N offset

    const int KT = K >> 6;                 // number of K-tiles
    const size_t KB = (size_t)KT << 10;    // bytes per 16-row block-row

    // A staging: thread copies chunk s = tid + 256*i (16B); m-block s>>6,
    // in-block chunk s&63. Global tiled source is contiguous per m-block.
    const int8_t* gA[2];
#pragma unroll
    for (int i = 0; i < 2; ++i) {
        int s = tid + 256 * i;
        gA[i] = A + (size_t)((brow >> 4) + (s >> 6)) * KB + (s & 63) * 16;
    }
    // B frag pointer: lane lr=row-in-block, lk=16B chunk; frag nj adds nj blocks
    const int8_t* pB = Bt + (size_t)((bcol + wn) >> 4) * KB + lr * 64 + lk * 16;
    // A frag ds_read base: m-block (wm>>4)+mi, contiguous 1024B blocks
    const int offA = (wm >> 4) * 1024 + lr * 64 + lk * 16;

    i32x4 acc[4][4] = {};
    i32x4 bS0[4], bS1[4], afr[4];

#define STAGE(buf, t)                                                   \
    gl16(gA[0] + (size_t)(t) * 1024, &lA[buf][tid * 16]);               \
    gl16(gA[1] + (size_t)(t) * 1024, &lA[buf][(tid + 256) * 16]);

#define LOADB(set, t)                                                   \
    _Pragma("unroll") for (int nj = 0; nj < 4; ++nj)                    \
        set[nj] = *(const i32x4*)(pB + (size_t)nj * KB + (size_t)(t) * 1024);

#define LOADA(buf)                                                      \
    _Pragma("unroll") for (int mi = 0; mi < 4; ++mi)                    \
        afr[mi] = *(const i32x4*)&lA[buf][offA + mi * 1024];

#define MFMA16(fb)                                                      \
    __builtin_amdgcn_s_setprio(1);                                      \
    _Pragma("unroll") for (int mi = 0; mi < 4; ++mi)                    \
    _Pragma("unroll") for (int nj = 0; nj < 4; ++nj)                    \
        acc[mi][nj] = __builtin_amdgcn_mfma_i32_16x16x64_i8(            \
            afr[mi], fb[nj], acc[mi][nj], 0, 0, 0);                     \
    __builtin_amdgcn_s_setprio(0);

    // ---- prologue: A0, B0, A1 in flight; wait A0+B0 ----
    STAGE(0, 0)
    LOADB(bS0, 0)
    STAGE(1, 1)
    WAIT_VM2
    BAR();

    const int T = KT;   // even, >= 4 (gated)
    for (int it = 0; it < (T - 2) / 2; ++it) {
        const int t0 = 2 * it;
        // tile t0: compute bS0; prefetch B(t0+1), stage A(t0+2)
        LOADB(bS1, t0 + 1)
        STAGE((t0 + 2) & 3, t0 + 2)
        LOADA(t0 & 3)
        WAIT_VM6            // retires B(t0) + A-stage(t0+1)
        BAR();
        MFMA16(bS0)
        // tile t0+1: compute bS1; prefetch B(t0+2), stage A(t0+3)
        LOADB(bS0, t0 + 2)
        STAGE((t0 + 3) & 3, t0 + 3)
        LOADA((t0 + 1) & 3)
        WAIT_VM6
        BAR();
        MFMA16(bS1)
    }
    // ---- tail: tiles T-2 (bS0), T-1 (bS1) ----
    LOADB(bS1, T - 1)
    LOADA((T - 2) & 3)
    WAIT_VM4                // retires B(T-2) + A-stage(T-1)
    BAR();
    MFMA16(bS0)
    WAIT_VM0                // B(T-1) in regs
    LOADA((T - 1) & 3)
    MFMA16(bS1)

    // ---- epilogue: y = acc * scales[row] + q(b)[col], relu.
    //      C/D layout: col = lane&15, row = (lane>>4)*4 + reg ----
    float bias[4];
#pragma unroll
    for (int nj = 0; nj < 4; ++nj) {
        float bv = b[bcol + wn + nj * 16 + lr];
        bias[nj] = rintf(pwb_clip(bv) * 127.f) * (1.f / 127.f);
    }

    const size_t orow = brow + wm + lk * 4;   // multiple of 4
    const size_t ocol = bcol + wn + lr;
    float4 scl[4];
#pragma unroll
    for (int mi = 0; mi < 4; ++mi)
        scl[mi] = *(const float4*)&scales[orow + mi * 16];

#pragma unroll
    for (int mi = 0; mi < 4; ++mi) {
        const float s0_ = scl[mi].x, s1_ = scl[mi].y, s2_ = scl[mi].z, s3_ = scl[mi].w;
#pragma unroll
        for (int nj = 0; nj < 4; ++nj) {
            float v0 = fmaf((float)acc[mi][nj][0], s0_, bias[nj]);
            float v1 = fmaf((float)acc[mi][nj][1], s1_, bias[nj]);
            float v2 = fmaf((float)acc[mi][nj][2], s2_, bias[nj]);
            float v3 = fmaf((float)acc[mi][nj][3], s3_, bias[nj]);
            float* cp = &C[(orow + mi * 16) * N + (ocol + nj * 16)];
            cp[0 * N] = fmaxf(v0, 0.f);
            cp[1 * N] = fmaxf(v1, 0.f);
            cp[2 * N] = fmaxf(v2, 0.f);
            cp[3 * N] = fmaxf(v3, 0.f);
        }
    }
#undef STAGE
#undef LOADB
#undef LOADA
#undef MFMA16
}

// ---- fallback (any shape): fp32, on-the-fly quantize ----
__global__ void pwb_fallback(const float* __restrict__ x, const float* __restrict__ W,
                             const float* __restrict__ b, float* __restrict__ out,
                             int M, int N, int K) {
    __shared__ float sA[16][17];
    __shared__ float sB[16][17];
    int tx = threadIdx.x, ty = threadIdx.y;
    int row = blockIdx.y * 16 + ty;
    int col = blockIdx.x * 16 + tx;
    float acc = 0.f;
    for (int kt = 0; kt < K; kt += 16) {
        sA[ty][tx] = (row < M && kt + tx < K) ? x[(size_t)row * K + kt + tx] : 0.f;
        float w = (kt + ty < K && col < N) ? W[(size_t)(kt + ty) * N + col] : 0.f;
        sB[ty][tx] = rintf(pwb_clip(w) * 127.f) * (1.f / 127.f);
        __syncthreads();
#pragma unroll
        for (int kk = 0; kk < 16; ++kk) acc += sA[ty][kk] * sB[kk][tx];
        __syncthreads();
    }
    if (row < M && col < N) {
        float v = acc + rintf(pwb_clip(b[col]) * 127.f) * (1.f / 127.f);
        out[(size_t)row * N + col] = fmaxf(v, 0.f);
    }
}

extern "C" void kernel_launch(void* const* d_in, const int* in_sizes, int n_in,
                              void* d_out, int out_size, void* d_ws, size_t ws_size,
                              hipStream_t stream) {
    const float* x = (const float*)d_in[0];
    const float* W = (const float*)d_in[1];
    const float* b = (const float*)d_in[2];
    float* out = (float*)d_out;

    const int DOUT = in_sizes[2];
    const int DIN  = in_sizes[1] / DOUT;
    const int M    = in_sizes[0] / DIN;

    size_t need = (size_t)M * DIN + (size_t)DIN * DOUT + (size_t)M * 4;
    const int T = DIN / BK;
    bool fast = (M % BM == 0) && (DOUT % BN == 0) &&
                (DIN % 256 == 0) && (DIN <= 2048) && (T >= 4) && ((T & 1) == 0) &&
                (ws_size >= need);

    if (fast) {
        int8_t* xq = (int8_t*)d_ws;                       // tiled [M/16][K/64][16][64]
        int8_t* Wq = xq + (size_t)M * DIN;                // tiled [N/16][K/64][16][64]
        float* scales = (float*)(Wq + (size_t)DIN * DOUT);// [M] f32

        const int xblocks = M / 4;
        const int wblocks = (DIN / 64) * (DOUT / 64);
        pwb_prep<<<xblocks + wblocks, 256, 0, stream>>>(x, W, xq, Wq, scales,
                                                        DIN, DOUT, xblocks);

        const int GM = M / BM, GN = DOUT / BN, nwg = GM * GN;
        pwb_gemmq<<<nwg, 256, 0, stream>>>(xq, Wq, scales, b, out, M, DOUT, DIN, GN, nwg);
    } else {
        dim3 g((DOUT + 15) / 16, (M + 15) / 16), blk(16, 16);
        pwb_fallback<<<g, blk, 0, stream>>>(x, W, b, out, M, DOUT, DIN);
    }
}